// Round 8
// baseline (489.157 us; speedup 1.0000x reference)
//
#include <hip/hip_runtime.h>

// out = tanh(((LN(z) @ W + b) * scale)/3)*3
// z (16384,1024) f32, W (1024,4096) f32, out (16384,4096) f32.
// Internal: zn and Wt in bf16 for MFMA (no fp32 MFMA on CDNA4).
#define M_DIM 16384
#define K_DIM 1024
#define N_DIM 4096
#define T_TILES (K_DIM / 64)   // 16 K-tiles of BK=64

typedef __bf16 bf16x8 __attribute__((ext_vector_type(8)));
typedef float f32x16 __attribute__((ext_vector_type(16)));

__device__ __forceinline__ unsigned short f2bf(float f) {
    union { float f; unsigned int i; } v; v.f = f;
    unsigned int r = v.i + 0x7fffu + ((v.i >> 16) & 1u);  // round-to-nearest-even
    return (unsigned short)(r >> 16);
}
__device__ __forceinline__ unsigned int pack2(float lo, float hi) {
    return ((unsigned int)f2bf(lo)) | (((unsigned int)f2bf(hi)) << 16);
}

// ---------------- Fused prep: LN (blocks [0,4096)) + W transpose (blocks [4096,8192)) ----------------
__global__ __launch_bounds__(256) void prep_kernel(
        const float* __restrict__ z,
        const float* __restrict__ gamma,
        const float* __restrict__ beta,
        unsigned short* __restrict__ zn,
        const float* __restrict__ W,
        unsigned short* __restrict__ Wt) {
    __shared__ float t[32][33];
    const int tid = threadIdx.x;
    if (blockIdx.x < M_DIM / 4) {
        const int wave = tid >> 6;
        const int lane = tid & 63;
        const size_t row = (size_t)blockIdx.x * 4 + wave;
        const float* zr = z + row * K_DIM;

        float4 x[4];
#pragma unroll
        for (int v = 0; v < 4; v++) x[v] = *(const float4*)(zr + v * 256 + lane * 4);

        float s = 0.f, ss = 0.f;
#pragma unroll
        for (int v = 0; v < 4; v++) {
            s  += x[v].x + x[v].y + x[v].z + x[v].w;
            ss += x[v].x * x[v].x + x[v].y * x[v].y + x[v].z * x[v].z + x[v].w * x[v].w;
        }
#pragma unroll
        for (int o = 32; o; o >>= 1) { s += __shfl_xor(s, o, 64); ss += __shfl_xor(ss, o, 64); }
        const float mean = s * (1.f / K_DIM);
        const float var = ss * (1.f / K_DIM) - mean * mean;
        const float rstd = rsqrtf(var + 1e-5f);

#pragma unroll
        for (int v = 0; v < 4; v++) {
            float4 g = *(const float4*)(gamma + v * 256 + lane * 4);
            float4 b = *(const float4*)(beta + v * 256 + lane * 4);
            float o0 = (x[v].x - mean) * rstd * g.x + b.x;
            float o1 = (x[v].y - mean) * rstd * g.y + b.y;
            float o2 = (x[v].z - mean) * rstd * g.z + b.z;
            float o3 = (x[v].w - mean) * rstd * g.w + b.w;
            uint2 q; q.x = pack2(o0, o1); q.y = pack2(o2, o3);
            *(uint2*)(zn + row * K_DIM + v * 256 + lane * 4) = q;
        }
    } else {
        const int bid = blockIdx.x - M_DIM / 4;
        const int tx = tid & 31, ty = tid >> 5;           // (32, 8)
        const int n0 = (bid & (N_DIM / 32 - 1)) * 32, k0 = (bid / (N_DIM / 32)) * 32;
#pragma unroll
        for (int j = 0; j < 32; j += 8)
            t[ty + j][tx] = W[(size_t)(k0 + ty + j) * N_DIM + n0 + tx];
        __syncthreads();
#pragma unroll
        for (int j = 0; j < 32; j += 8)
            Wt[(size_t)(n0 + ty + j) * K_DIM + k0 + tx] = f2bf(t[tx][ty + j]);
    }
}

// ---------------- GEMM: 256x256, 8 waves, BK=64, fragment-level pipelined K-loop ----------------
// LDS tile: 256 rows x 64 bf16. 16B-unit of (row, chunk c) = row*8 + (c ^ (row&7)).
// Staging thread tid fetches row (tid>>3)+64p, chunk (tid&7)^((tid>>3)&7) (linear LDS dest, G21).
// K-tile = 32 MFMA/wave split into 4 groups of 8; reads for the next group are issued UNDER the
// current group's MFMAs with counted lgkmcnt waits (ledger below); next tile's first group (G0')
// is read mid-tile after a vmcnt(0)+barrier (confirms tile t+1's staging, issued 1.5 tiles ago).
// The pre-STAGE barrier sits between the last two MFMA groups; the tile boundary has NO barrier.
// Per-wave lgkm ledger (steady state; issue order G0' | G2 G1 | G3 G0'):
//   entry: G0'(8) out. +G2(4) +G1(8) -> lgkm(12)=G0' done -> M_G0 ; lgkm(8)=G2 done -> M_G2
//   +G3(4) ; vmcnt(0)+bar ; +G0'(8) -> lgkm(12)=G1 done -> M_G1 ; lgkm(8)=G3 done
//   -> bar+STAGE(t+2) -> M_G3.   Tail t=T-1: skip G0', counts 4/0.
__device__ __forceinline__ void async_copy16(const unsigned short* g, unsigned short* l) {
    __builtin_amdgcn_global_load_lds(
        (const __attribute__((address_space(1))) unsigned int*)g,
        (__attribute__((address_space(3))) unsigned int*)l,
        16, 0, 0);
}

__global__ __launch_bounds__(512, 2) void gemm_kernel(
        const unsigned short* __restrict__ A,   // zn, (M, K) bf16
        const unsigned short* __restrict__ B,   // Wt, (N, K) bf16
        const float* __restrict__ bias,
        const float* __restrict__ scale,
        float* __restrict__ out) {
    __shared__ __align__(16) unsigned short As[2][256 * 64];   // 2 x 32 KB
    __shared__ __align__(16) unsigned short Bs[2][256 * 64];   // 2 x 32 KB  (total 128 KB)

    const int tid = threadIdx.x;
    const int wave = tid >> 6, lane = tid & 63;
    const int wm = wave >> 2, wn = wave & 3;     // 2x4 wave grid, each 128x64 of the 256x256 tile
    const int l31 = lane & 31, lhi = lane >> 5;

    // T1: XCD-aware block swizzle. nwg = 1024, divisible by 8.
    const int bid = blockIdx.y * gridDim.x + blockIdx.x;
    const int id2 = (bid & 7) * 128 + (bid >> 3);
    const int bm = id2 >> 4, bn = id2 & 15;

    // Staging source (per 256x64 tile): thread tid covers units {512p + tid}, p=0..3.
    const int r0 = tid >> 3;
    const int c0 = ((tid & 7) ^ ((tid >> 3) & 7)) << 3;
    const unsigned short* agA = A + (size_t)(bm * 256 + r0) * K_DIM + c0;
    const unsigned short* agB = B + (size_t)(bn * 256 + r0) * K_DIM + c0;
    const int ldsu = wave * 512;

#define STAGE(t_, s_) do { \
        const unsigned short* gA_ = agA + (t_) * 64; \
        const unsigned short* gB_ = agB + (t_) * 64; \
        async_copy16(gA_,                 &As[s_][ldsu]); \
        async_copy16(gA_ +  64 * K_DIM,   &As[s_][ldsu + 4096]); \
        async_copy16(gA_ + 128 * K_DIM,   &As[s_][ldsu + 8192]); \
        async_copy16(gA_ + 192 * K_DIM,   &As[s_][ldsu + 12288]); \
        async_copy16(gB_,                 &Bs[s_][ldsu]); \
        async_copy16(gB_ +  64 * K_DIM,   &Bs[s_][ldsu + 4096]); \
        async_copy16(gB_ + 128 * K_DIM,   &Bs[s_][ldsu + 8192]); \
        async_copy16(gB_ + 192 * K_DIM,   &Bs[s_][ldsu + 12288]); } while (0)

    f32x16 acc[4][2] = {};
    bf16x8 a0[2][2], a1[2][2], a2[2][2], a3[2][2], b0[2][2], b1[2][2];
    const int rsw = l31 & 7;

    // Read a 4-frag group. kp selects K half (ks = 2*kp + q); chunk c = kp*4 + q*2 + lhi.
#define RA(dst_, s_, h_, kp_) do { \
        const unsigned short* as_ = As[s_]; \
        _Pragma("unroll") \
        for (int i_ = 0; i_ < 2; ++i_) \
        _Pragma("unroll") \
        for (int q_ = 0; q_ < 2; ++q_) \
            dst_[i_][q_] = *(const bf16x8*)&as_[(wm * 128 + (h_) * 64 + i_ * 32 + l31) * 64 + ((((kp_) * 4 + q_ * 2 + lhi) ^ rsw) << 3)]; } while (0)
#define RB(dst_, s_, kp_) do { \
        const unsigned short* bs_ = Bs[s_]; \
        _Pragma("unroll") \
        for (int j_ = 0; j_ < 2; ++j_) \
        _Pragma("unroll") \
        for (int q_ = 0; q_ < 2; ++q_) \
            dst_[j_][q_] = *(const bf16x8*)&bs_[(wn * 64 + j_ * 32 + l31) * 64 + ((((kp_) * 4 + q_ * 2 + lhi) ^ rsw) << 3)]; } while (0)
#define MFG(r_, aa_, bb_) do { \
        _Pragma("unroll") \
        for (int q_ = 0; q_ < 2; ++q_) \
        _Pragma("unroll") \
        for (int i_ = 0; i_ < 2; ++i_) \
        _Pragma("unroll") \
        for (int j_ = 0; j_ < 2; ++j_) \
            acc[(r_) + i_][j_] = __builtin_amdgcn_mfma_f32_32x32x16_bf16(aa_[i_][q_], bb_[j_][q_], acc[(r_) + i_][j_], 0, 0, 0); } while (0)

    // Prologue: stage tiles 0,1; confirm tile 0; pre-read its G0 (a0: h0/ks01, b0: ks01).
    STAGE(0, 0);
    STAGE(1, 1);
    asm volatile("s_waitcnt vmcnt(8)" ::: "memory");
    __builtin_amdgcn_s_barrier();
    asm volatile("" ::: "memory");
    RA(a0, 0, 0, 0); RB(b0, 0, 0);                      // 8 reads outstanding

#pragma unroll 2
    for (int t = 0; t < T_TILES; ++t) {
        const int s = t & 1;

        RA(a2, s, 1, 0);                                // G2: 4 reads (h1, ks01)
        RA(a1, s, 0, 1); RB(b1, s, 1);                  // G1: 8 reads (h0/b, ks23)

        asm volatile("s_waitcnt lgkmcnt(12)" ::: "memory");   // G0 ready
        __builtin_amdgcn_sched_barrier(0);
        __builtin_amdgcn_s_setprio(1);
        MFG(0, a0, b0);                                 // acc[0..1] += a0*b0 (ks01)
        __builtin_amdgcn_s_setprio(0);

        asm volatile("s_waitcnt lgkmcnt(8)" ::: "memory");    // G2 ready
        __builtin_amdgcn_sched_barrier(0);
        __builtin_amdgcn_s_setprio(1);
        MFG(2, a2, b0);                                 // acc[2..3] += a2*b0 ; a0,b0 now free
        __builtin_amdgcn_s_setprio(0);

        RA(a3, s, 1, 1);                                // G3: 4 reads (h1, ks23)
        if (t + 1 < T_TILES) {
            // Tile t+1's staging (issued 1.5 tiles ago) is the only outstanding vm set.
            asm volatile("s_waitcnt vmcnt(0)" ::: "memory");
            __builtin_amdgcn_s_barrier();
            asm volatile("" ::: "memory");
            RA(a0, s ^ 1, 0, 0); RB(b0, s ^ 1, 0);      // G0': 8 reads of next tile
            asm volatile("s_waitcnt lgkmcnt(12)" ::: "memory");  // G1 ready
        } else {
            asm volatile("s_waitcnt lgkmcnt(4)" ::: "memory");   // G1 ready (no G0')
        }
        __builtin_amdgcn_sched_barrier(0);
        __builtin_amdgcn_s_setprio(1);
        MFG(0, a1, b1);                                 // acc[0..1] += a1*b1 (ks23)
        __builtin_amdgcn_s_setprio(0);

        if (t + 1 < T_TILES) {
            asm volatile("s_waitcnt lgkmcnt(8)" ::: "memory");   // G3 ready (leaves G0')
        } else {
            asm volatile("s_waitcnt lgkmcnt(0)" ::: "memory");
        }
        __builtin_amdgcn_sched_barrier(0);
        if (t + 2 < T_TILES) {
            // All waves' reads of buf s are retired; safe to overwrite. Covered by M_G1/M_G3.
            __builtin_amdgcn_s_barrier();
            asm volatile("" ::: "memory");
            STAGE(t + 2, s);
        }
        __builtin_amdgcn_s_setprio(1);
        MFG(2, a3, b1);                                 // acc[2..3] += a3*b1
        __builtin_amdgcn_s_setprio(0);
    }
#undef STAGE
#undef RA
#undef RB
#undef MFG

    // Epilogue: out = 3*tanh(x/3) = 3 - 6/(exp2(x*2/(3 ln2)) + 1); saturates correctly at +-inf.
    const float mfac = scale[0] * 0.96179669392236f;   // scale * 2/(3*ln2)
#pragma unroll
    for (int j = 0; j < 2; ++j) {
        const int gcol = bn * 256 + wn * 64 + j * 32 + l31;
        const float bv = bias[gcol];
#pragma unroll
        for (int i = 0; i < 4; ++i) {
            const int rbase = bm * 256 + wm * 128 + i * 32 + 4 * lhi;
#pragma unroll
            for (int r = 0; r < 16; ++r) {
                const int grow = rbase + (r & 3) + 8 * (r >> 2);
                float tv = (acc[i][j][r] + bv) * mfac;
                float e = __builtin_amdgcn_exp2f(tv);
                out[(size_t)grow * N_DIM + gcol] = 3.f - 6.f * __builtin_amdgcn_rcpf(e + 1.f);
            }
        }
    }
}

extern "C" void kernel_launch(void* const* d_in, const int* in_sizes, int n_in,
                              void* d_out, int out_size, void* d_ws, size_t ws_size,
                              hipStream_t stream) {
    const float* z     = (const float*)d_in[0];
    const float* gamma = (const float*)d_in[1];
    const float* beta  = (const float*)d_in[2];
    const float* W     = (const float*)d_in[3];
    const float* b     = (const float*)d_in[4];
    const float* scale = (const float*)d_in[5];
    float* out = (float*)d_out;

    unsigned short* zn = (unsigned short*)d_ws;                 // 16384*1024 bf16 = 32 MB
    unsigned short* Wt = zn + (size_t)M_DIM * K_DIM;            // 4096*1024 bf16  =  8 MB

    prep_kernel<<<M_DIM / 4 + (N_DIM / 32) * (K_DIM / 32), 256, 0, stream>>>(z, gamma, beta, zn, W, Wt);
    gemm_kernel<<<dim3(N_DIM / 256, M_DIM / 256), 512, 0, stream>>>(zn, Wt, b, scale, out);
}

// Round 9
// 475.322 us; speedup vs baseline: 1.0291x; 1.0291x over previous
//
#include <hip/hip_runtime.h>

// out = tanh(((LN(z) @ W + b) * scale)/3)*3
// z (16384,1024) f32, W (1024,4096) f32, out (16384,4096) f32.
// Internal: zn and Wt in bf16 for MFMA (no fp32 MFMA on CDNA4).
#define M_DIM 16384
#define K_DIM 1024
#define N_DIM 4096
#define T_TILES (K_DIM / 32)   // 32 K-tiles of BK=32

typedef __bf16 bf16x8 __attribute__((ext_vector_type(8)));
typedef float f32x4 __attribute__((ext_vector_type(4)));

__device__ __forceinline__ unsigned short f2bf(float f) {
    union { float f; unsigned int i; } v; v.f = f;
    unsigned int r = v.i + 0x7fffu + ((v.i >> 16) & 1u);  // round-to-nearest-even
    return (unsigned short)(r >> 16);
}
__device__ __forceinline__ unsigned int pack2(float lo, float hi) {
    return ((unsigned int)f2bf(lo)) | (((unsigned int)f2bf(hi)) << 16);
}

// ---------------- Fused prep: LN (blocks [0,4096)) + W transpose (blocks [4096,8192)) ----------------
__global__ __launch_bounds__(256) void prep_kernel(
        const float* __restrict__ z,
        const float* __restrict__ gamma,
        const float* __restrict__ beta,
        unsigned short* __restrict__ zn,
        const float* __restrict__ W,
        unsigned short* __restrict__ Wt) {
    __shared__ float t[32][33];
    const int tid = threadIdx.x;
    if (blockIdx.x < M_DIM / 4) {
        const int wave = tid >> 6;
        const int lane = tid & 63;
        const size_t row = (size_t)blockIdx.x * 4 + wave;
        const float* zr = z + row * K_DIM;

        float4 x[4];
#pragma unroll
        for (int v = 0; v < 4; v++) x[v] = *(const float4*)(zr + v * 256 + lane * 4);

        float s = 0.f, ss = 0.f;
#pragma unroll
        for (int v = 0; v < 4; v++) {
            s  += x[v].x + x[v].y + x[v].z + x[v].w;
            ss += x[v].x * x[v].x + x[v].y * x[v].y + x[v].z * x[v].z + x[v].w * x[v].w;
        }
#pragma unroll
        for (int o = 32; o; o >>= 1) { s += __shfl_xor(s, o, 64); ss += __shfl_xor(ss, o, 64); }
        const float mean = s * (1.f / K_DIM);
        const float var = ss * (1.f / K_DIM) - mean * mean;
        const float rstd = rsqrtf(var + 1e-5f);

#pragma unroll
        for (int v = 0; v < 4; v++) {
            float4 g = *(const float4*)(gamma + v * 256 + lane * 4);
            float4 b = *(const float4*)(beta + v * 256 + lane * 4);
            float o0 = (x[v].x - mean) * rstd * g.x + b.x;
            float o1 = (x[v].y - mean) * rstd * g.y + b.y;
            float o2 = (x[v].z - mean) * rstd * g.z + b.z;
            float o3 = (x[v].w - mean) * rstd * g.w + b.w;
            uint2 q; q.x = pack2(o0, o1); q.y = pack2(o2, o3);
            *(uint2*)(zn + row * K_DIM + v * 256 + lane * 4) = q;
        }
    } else {
        const int bid = blockIdx.x - M_DIM / 4;
        const int tx = tid & 31, ty = tid >> 5;           // (32, 8)
        const int n0 = (bid & (N_DIM / 32 - 1)) * 32, k0 = (bid / (N_DIM / 32)) * 32;
#pragma unroll
        for (int j = 0; j < 32; j += 8)
            t[ty + j][tx] = W[(size_t)(k0 + ty + j) * N_DIM + n0 + tx];
        __syncthreads();
#pragma unroll
        for (int j = 0; j < 32; j += 8)
            Wt[(size_t)(n0 + ty + j) * K_DIM + k0 + tx] = f2bf(t[tx][ty + j]);
    }
}

// ---------------- GEMM: m201-faithful port. 256x256, 8 waves, 16x16x32 MFMA ----------------
// Ring-4 LDS of 256x32 K-tiles (R1's proven plan): unit u(row, c in [0,4)) = row*4 + (c ^ ((row>>1)&3)).
// Staging thread tid fetches row (tid>>2)(+128), chunk (tid&3)^((tid>>3)&3) -> linear LDS dest.
// Per K-tile: 2 phases, each {ds-reads at top; stage 2 gloads; barrier; lgkm(0); setprio;
//   16 x mfma_16x16x32 (one 64-row half x 4 n-tiles); setprio; [ph2 only: counted vmcnt]; barrier}.
// B-frags (4) read once in ph1, register-held through ph2 -> 12 ds_read_b128 / tile / wave.
// vmcnt ledger (lead 3): at ph2 of t, outstanding = tiles t+1,t+2,t+3 (4 loads each);
//   vmcnt(8) retires t+1's 4. Tail: t=T-3 -> vmcnt(4), t=T-2 -> vmcnt(0), t=T-1 -> none.
__device__ __forceinline__ void async_copy16(const unsigned short* g, unsigned short* l) {
    __builtin_amdgcn_global_load_lds(
        (const __attribute__((address_space(1))) unsigned int*)g,
        (__attribute__((address_space(3))) unsigned int*)l,
        16, 0, 0);
}

__global__ __launch_bounds__(512, 2) void gemm_kernel(
        const unsigned short* __restrict__ A,   // zn, (M, K) bf16
        const unsigned short* __restrict__ B,   // Wt, (N, K) bf16
        const float* __restrict__ bias,
        const float* __restrict__ scale,
        float* __restrict__ out) {
    __shared__ __align__(16) unsigned short As[4][256 * 32];   // 4 x 16 KB
    __shared__ __align__(16) unsigned short Bs[4][256 * 32];   // 4 x 16 KB  (total 128 KB)

    const int tid = threadIdx.x;
    const int wave = tid >> 6, lane = tid & 63;
    const int wm = wave >> 2, wn = wave & 3;     // 2x4 wave grid, each 128x64 of the 256x256 tile
    const int rl = lane & 15;                    // 16x16 frag row/col index
    const int kc = lane >> 4;                    // k-chunk 0..3 (8 consecutive k each)
    const int swz = (rl >> 1) & 3;               // layout XOR (row base is a multiple of 16)

    // T1: XCD-aware block swizzle. nwg = 1024, divisible by 8.
    const int bid = blockIdx.y * gridDim.x + blockIdx.x;
    const int id2 = (bid & 7) * 128 + (bid >> 3);
    const int bm = id2 >> 4, bn = id2 & 15;

    // Staging source: thread tid covers unit u = q*512 + tid of each 256x32 tile.
    const int r0 = tid >> 2;
    const int c0 = ((tid & 3) ^ ((tid >> 3) & 3)) << 3;
    const unsigned short* agA = A + (size_t)(bm * 256 + r0) * K_DIM + c0;
    const unsigned short* agB = B + (size_t)(bn * 256 + r0) * K_DIM + c0;
    const int ldsu = wave * 512;

#define STAGE_A(t_, s_) do { \
        const unsigned short* g_ = agA + (t_) * 32; \
        async_copy16(g_,                 &As[s_][ldsu]); \
        async_copy16(g_ + 128 * K_DIM,   &As[s_][4096 + ldsu]); } while (0)
#define STAGE_B(t_, s_) do { \
        const unsigned short* g_ = agB + (t_) * 32; \
        async_copy16(g_,                 &Bs[s_][ldsu]); \
        async_copy16(g_ + 128 * K_DIM,   &Bs[s_][4096 + ldsu]); } while (0)

    f32x4 acc[8][4] = {};    // [mt 0..7][nt 0..3] 16x16 tiles; 128 VGPR total
    bf16x8 a[4], b[4];

    // Frag reads: lane reads row (base + rl), k-chunk kc -> elem (row*32 + ((kc^swz)<<3)).
#define READ_A(s_, mh_) do { \
        const unsigned short* as_ = As[s_]; \
        _Pragma("unroll") \
        for (int mt_ = 0; mt_ < 4; ++mt_) \
            a[mt_] = *(const bf16x8*)&as_[(wm * 128 + (mh_) * 64 + mt_ * 16 + rl) * 32 + ((kc ^ swz) << 3)]; } while (0)
#define READ_B(s_) do { \
        const unsigned short* bs_ = Bs[s_]; \
        _Pragma("unroll") \
        for (int nt_ = 0; nt_ < 4; ++nt_) \
            b[nt_] = *(const bf16x8*)&bs_[(wn * 64 + nt_ * 16 + rl) * 32 + ((kc ^ swz) << 3)]; } while (0)
#define MFG(mh_) do { \
        _Pragma("unroll") \
        for (int mt_ = 0; mt_ < 4; ++mt_) \
        _Pragma("unroll") \
        for (int nt_ = 0; nt_ < 4; ++nt_) \
            acc[(mh_) * 4 + mt_][nt_] = __builtin_amdgcn_mfma_f32_16x16x32_bf16(a[mt_], b[nt_], acc[(mh_) * 4 + mt_][nt_], 0, 0, 0); } while (0)

    // Prologue: stage tiles 0,1,2 (12 loads); retire tile 0's 4; join.
    STAGE_A(0, 0); STAGE_B(0, 0);
    STAGE_A(1, 1); STAGE_B(1, 1);
    STAGE_A(2, 2); STAGE_B(2, 2);
    asm volatile("s_waitcnt vmcnt(8)" ::: "memory");
    __builtin_amdgcn_s_barrier();
    asm volatile("" ::: "memory");

#pragma unroll 4
    for (int t = 0; t < T_TILES; ++t) {
        const int s = t & 3, ss = (t + 3) & 3;

        // ---- phase 1: reads (A-half 0 + B), stage A(t+3), barrier, 16 MFMA ----
        READ_A(s, 0); READ_B(s);
        if (t + 3 < T_TILES) STAGE_A(t + 3, ss);   // writes slot (t-1)&3: readers done last tile
        asm volatile("" ::: "memory");
        __builtin_amdgcn_s_barrier();
        asm volatile("s_waitcnt lgkmcnt(0)" ::: "memory");
        __builtin_amdgcn_sched_barrier(0);
        __builtin_amdgcn_s_setprio(1);
        MFG(0);
        __builtin_amdgcn_s_setprio(0);
        asm volatile("" ::: "memory");
        __builtin_amdgcn_s_barrier();
        asm volatile("" ::: "memory");

        // ---- phase 2: reads (A-half 1; B held), stage B(t+3), barrier, 16 MFMA, vmcnt ----
        READ_A(s, 1);
        if (t + 3 < T_TILES) STAGE_B(t + 3, ss);
        asm volatile("" ::: "memory");
        __builtin_amdgcn_s_barrier();
        asm volatile("s_waitcnt lgkmcnt(0)" ::: "memory");
        __builtin_amdgcn_sched_barrier(0);
        __builtin_amdgcn_s_setprio(1);
        MFG(1);
        __builtin_amdgcn_s_setprio(0);
        if (t < T_TILES - 1) {
            if (t < T_TILES - 3)       asm volatile("s_waitcnt vmcnt(8)" ::: "memory");
            else if (t == T_TILES - 3) asm volatile("s_waitcnt vmcnt(4)" ::: "memory");
            else                       asm volatile("s_waitcnt vmcnt(0)" ::: "memory");
            __builtin_amdgcn_s_barrier();
            asm volatile("" ::: "memory");
        }
    }
#undef STAGE_A
#undef STAGE_B
#undef READ_A
#undef READ_B
#undef MFG

    // Epilogue: out = 3*tanh(x/3) = 3 - 6/(exp2(x*2/(3 ln2)) + 1); saturates correctly at +-inf.
    // 16x16 C/D layout: col = lane&15, row = (lane>>4)*4 + r  [m89/m91-verified].
    const float mfac = scale[0] * 0.96179669392236f;   // scale * 2/(3*ln2)
#pragma unroll
    for (int nt = 0; nt < 4; ++nt) {
        const int gcol = bn * 256 + wn * 64 + nt * 16 + rl;
        const float bv = bias[gcol];
#pragma unroll
        for (int mt = 0; mt < 8; ++mt) {
            const int rbase = bm * 256 + wm * 128 + mt * 16 + kc * 4;
#pragma unroll
            for (int r = 0; r < 4; ++r) {
                const int grow = rbase + r;
                float tv = (acc[mt][nt][r] + bv) * mfac;
                float e = __builtin_amdgcn_exp2f(tv);
                out[(size_t)grow * N_DIM + gcol] = 3.f - 6.f * __builtin_amdgcn_rcpf(e + 1.f);
            }
        }
    }
}

extern "C" void kernel_launch(void* const* d_in, const int* in_sizes, int n_in,
                              void* d_out, int out_size, void* d_ws, size_t ws_size,
                              hipStream_t stream) {
    const float* z     = (const float*)d_in[0];
    const float* gamma = (const float*)d_in[1];
    const float* beta  = (const float*)d_in[2];
    const float* W     = (const float*)d_in[3];
    const float* b     = (const float*)d_in[4];
    const float* scale = (const float*)d_in[5];
    float* out = (float*)d_out;

    unsigned short* zn = (unsigned short*)d_ws;                 // 16384*1024 bf16 = 32 MB
    unsigned short* Wt = zn + (size_t)M_DIM * K_DIM;            // 4096*1024 bf16  =  8 MB

    prep_kernel<<<M_DIM / 4 + (N_DIM / 32) * (K_DIM / 32), 256, 0, stream>>>(z, gamma, beta, zn, W, Wt);
    gemm_kernel<<<dim3(N_DIM / 256, M_DIM / 256), 512, 0, stream>>>(zn, Wt, b, scale, out);
}